// Round 4
// baseline (3966.996 us; speedup 1.0000x reference)
//
// Round 4: resubmit R3 bisection (never ran — GPU timeout), hardened:
// - fp32 VALU attention (no MFMA/swizzle) replaces flash path; GEMMs unchanged from R2.
// - q_rf overlaid on dead WqT/WkT/WvT region (ws 464->432 MB).
// PASS -> attention path was the R2 bug; FAIL ~0.8 -> GEMM/elementwise path.
#include <hip/hip_runtime.h>
#include <stdint.h>

static constexpr int B_   = 2;
static constexpr int S_   = 2048;
static constexpr int H_   = 2048;
static constexpr int NH_  = 16;
static constexpr int NKV_ = 8;
static constexpr int HD_  = 128;
static constexpr int I_   = 6144;
static constexpr int M_   = B_ * S_;   // 4096 token rows

typedef __attribute__((ext_vector_type(8))) short bf16x8;
typedef __attribute__((ext_vector_type(4))) float f32x4;
typedef __attribute__((ext_vector_type(4))) float f4;

__device__ __forceinline__ unsigned short f2bf(float f) {
  union { float f; unsigned u; } v; v.f = f;
  unsigned r = v.u + 0x7fffu + ((v.u >> 16) & 1u);
  return (unsigned short)(r >> 16);
}
__device__ __forceinline__ float bf2f(unsigned short h) {
  union { unsigned u; float f; } v; v.u = ((unsigned)h) << 16;
  return v.f;
}
__device__ __forceinline__ void mfma16(f32x4& d, bf16x8 a, bf16x8 b) {
  asm("v_mfma_f32_16x16x32_bf16 %0, %1, %2, %0" : "+v"(d) : "v"(a), "v"(b));
}
__device__ __forceinline__ void gl_lds16(const void* g, void* l) {
  __builtin_amdgcn_global_load_lds((const __attribute__((address_space(1))) void*)g,
                                   (__attribute__((address_space(3))) void*)l, 16, 0, 0);
}

// ---------------- GEMM: C[M,N] = A[M,K](bf16) * Bt[N,K](bf16)^T ----------------
template <int OUT_BF16>
__global__ __launch_bounds__(256, 2)
void gemm_bt(const unsigned short* __restrict__ A, const unsigned short* __restrict__ Bt,
             void* __restrict__ Cout, int M, int N, int K) {
  __shared__ unsigned short sA[2][128][32];
  __shared__ unsigned short sB[2][128][32];
  const int tid  = threadIdx.x;
  const int lane = tid & 63, wave = tid >> 6;
  const int lo = lane & 15, hi = lane >> 4;

  // T1: XCD-aware bijective block swizzle (all grids have nwg % 8 == 0)
  const int nbx = gridDim.x;
  int bid = blockIdx.y * nbx + blockIdx.x;
  const int nwg = nbx * gridDim.y;
  if ((nwg & 7) == 0) bid = (bid & 7) * (nwg >> 3) + (bid >> 3);
  const int m0 = (bid / nbx) * 128, n0 = (bid % nbx) * 128;

  const int wm = (wave >> 1) * 64, wn = (wave & 1) * 64;

  const int arow = tid >> 2;            // 0..63 (and +64)
  const int achk = (tid & 3) * 8;       // element offset (8 bf16 = 16B)
  const unsigned short* gA = A  + (long)(m0 + arow) * K + achk;
  const unsigned short* gB = Bt + (long)(n0 + arow) * K + achk;

  f32x4 acc[4][4] = {};
  const int nk = K >> 5;

  auto stage = [&](int buf, int kt) {
    const unsigned short* a = gA + kt * 32;
    const unsigned short* b = gB + kt * 32;
    gl_lds16(a,            &sA[buf][arow][achk]);
    gl_lds16(a + 64L * K,  &sA[buf][arow + 64][achk]);
    gl_lds16(b,            &sB[buf][arow][achk]);
    gl_lds16(b + 64L * K,  &sB[buf][arow + 64][achk]);
  };

  stage(0, 0);
  __syncthreads();
  for (int kt = 0; kt < nk; ++kt) {
    const int buf = kt & 1;
    if (kt + 1 < nk) stage(buf ^ 1, kt + 1);
    bf16x8 af[4], bv[4];
#pragma unroll
    for (int i = 0; i < 4; ++i) af[i] = *(const bf16x8*)&sA[buf][wm + i * 16 + lo][hi * 8];
#pragma unroll
    for (int j = 0; j < 4; ++j) bv[j] = *(const bf16x8*)&sB[buf][wn + j * 16 + lo][hi * 8];
#pragma unroll
    for (int i = 0; i < 4; ++i)
#pragma unroll
      for (int j = 0; j < 4; ++j) mfma16(acc[i][j], af[i], bv[j]);
    __syncthreads();
  }

  const int rbase = m0 + wm + hi * 4;
  const int cbase = n0 + wn + lo;
  if (OUT_BF16) {
    unsigned short* C = (unsigned short*)Cout;
#pragma unroll
    for (int i = 0; i < 4; ++i)
#pragma unroll
      for (int j = 0; j < 4; ++j)
#pragma unroll
        for (int r = 0; r < 4; ++r)
          C[(long)(rbase + i * 16 + r) * N + cbase + j * 16] = f2bf(acc[i][j][r]);
  } else {
    float* C = (float*)Cout;
#pragma unroll
    for (int i = 0; i < 4; ++i)
#pragma unroll
      for (int j = 0; j < 4; ++j)
#pragma unroll
        for (int r = 0; r < 4; ++r)
          C[(long)(rbase + i * 16 + r) * N + cbase + j * 16] = acc[i][j][r];
  }
}

// ------------- transpose + fp32->bf16 convert (per-z-slice) -------------
// dst[z][c][r] = src[z][r][c];  R,C multiples of 32.
__global__ __launch_bounds__(256)
void transpose_cvt_z(const float* __restrict__ src, unsigned short* __restrict__ dst,
                     int R, int C) {
  __shared__ float tle[32][33];
  const long slice = (long)blockIdx.z * R * C;
  const int c0 = blockIdx.x * 32, r0 = blockIdx.y * 32;
  const int tx = threadIdx.x & 31, ty = threadIdx.x >> 5;  // ty 0..7
#pragma unroll
  for (int i = 0; i < 4; ++i)
    tle[ty + i * 8][tx] = src[slice + (long)(r0 + ty + i * 8) * C + c0 + tx];
  __syncthreads();
#pragma unroll
  for (int i = 0; i < 4; ++i)
    dst[slice + (long)(c0 + ty + i * 8) * R + r0 + tx] = f2bf(tle[tx][ty + i * 8]);
}

// ------------- block reduce helper -------------
__device__ __forceinline__ float block_reduce_sum(float v, float* red) {
  const int lane = threadIdx.x & 63, wave = threadIdx.x >> 6;
#pragma unroll
  for (int off = 1; off < 64; off <<= 1) v += __shfl_xor(v, off, 64);
  if (lane == 0) red[wave] = v;
  __syncthreads();
  return red[0] + red[1] + red[2] + red[3];
}

// ------------- fused RMSNorm(emb)*in_w || RMSNorm(hid)*hn_w -> x bf16 [M][4096] -------------
__global__ __launch_bounds__(256)
void rms_concat(const float* __restrict__ emb, const float* __restrict__ hid,
                const float* __restrict__ in_w, const float* __restrict__ hn_w,
                unsigned short* __restrict__ x) {
  __shared__ float red[8];
  const int row = blockIdx.x, tid = threadIdx.x;
  {
    const float* p = emb + (long)row * H_;
    f4 a = ((const f4*)p)[tid];
    f4 b = ((const f4*)p)[tid + 256];
    float ss = a.x*a.x + a.y*a.y + a.z*a.z + a.w*a.w + b.x*b.x + b.y*b.y + b.z*b.z + b.w*b.w;
    float sc = rsqrtf(block_reduce_sum(ss, red) * (1.0f / H_) + 1e-6f);
    unsigned short* xo = x + (long)row * (2 * H_);
#pragma unroll
    for (int j = 0; j < 4; ++j) {
      xo[tid * 4 + j]        = f2bf(a[j] * sc * in_w[tid * 4 + j]);
      xo[1024 + tid * 4 + j] = f2bf(b[j] * sc * in_w[1024 + tid * 4 + j]);
    }
  }
  {
    const float* p = hid + (long)row * H_;
    f4 a = ((const f4*)p)[tid];
    f4 b = ((const f4*)p)[tid + 256];
    float ss = a.x*a.x + a.y*a.y + a.z*a.z + a.w*a.w + b.x*b.x + b.y*b.y + b.z*b.z + b.w*b.w;
    float sc = rsqrtf(block_reduce_sum(ss, red + 4) * (1.0f / H_) + 1e-6f);
    unsigned short* xo = x + (long)row * (2 * H_) + H_;
#pragma unroll
    for (int j = 0; j < 4; ++j) {
      xo[tid * 4 + j]        = f2bf(a[j] * sc * hn_w[tid * 4 + j]);
      xo[1024 + tid * 4 + j] = f2bf(b[j] * sc * hn_w[1024 + tid * 4 + j]);
    }
  }
}

// ------------- RoPE + layout: (M, nh*128) fp32 -> (B, nh, S, 128) fp32 -------------
__global__ __launch_bounds__(256)
void rope_qkv(const float* __restrict__ qf, const float* __restrict__ kf, const float* __restrict__ vf,
              const float* __restrict__ cosb, const float* __restrict__ sinb,
              float* __restrict__ q_rf, float* __restrict__ k_rf, float* __restrict__ v_rf) {
  const int tok = blockIdx.x;         // b*S + s
  const int b = tok >> 11, s = tok & (S_ - 1);
  const int tid = threadIdx.x;
  __shared__ float cs[HD_], sn[HD_];
  if (tid < HD_) { cs[tid] = cosb[(long)tok * HD_ + tid]; sn[tid] = sinb[(long)tok * HD_ + tid]; }
  __syncthreads();
  const float* qrow = qf + (long)tok * (NH_ * HD_);
  for (int e = tid; e < NH_ * HD_; e += 256) {
    int hh = e >> 7, d = e & 127;
    float xv = qrow[e];
    float o = (d < 64) ? -qrow[e + 64] : qrow[e - 64];
    q_rf[((long)(b * NH_ + hh) * S_ + s) * HD_ + d] = xv * cs[d] + o * sn[d];
  }
  const float* krow = kf + (long)tok * (NKV_ * HD_);
  for (int e = tid; e < NKV_ * HD_; e += 256) {
    int hh = e >> 7, d = e & 127;
    float xv = krow[e];
    float o = (d < 64) ? -krow[e + 64] : krow[e - 64];
    k_rf[((long)(b * NKV_ + hh) * S_ + s) * HD_ + d] = xv * cs[d] + o * sn[d];
  }
  const float* vrow = vf + (long)tok * (NKV_ * HD_);
  for (int e = tid; e < NKV_ * HD_; e += 256) {
    int hh = e >> 7, d = e & 127;
    v_rf[((long)(b * NKV_ + hh) * S_ + s) * HD_ + d] = vrow[e];
  }
}

// ------------- SIMPLE fp32 attention (diagnostic, no MFMA/no swizzle) -------------
// Grid (S/32, NH, B), block 256 (4 waves). 32 query rows per block.
// Lane = (half 0/1)*32 + key-lane kl. Wave w handles rows w*8 + rp*2 + half.
__global__ __launch_bounds__(256, 2)
void attn_simple(const float* __restrict__ q_rf, const float* __restrict__ k_rf,
                 const float* __restrict__ v_rf, const float* __restrict__ cache_k,
                 const float* __restrict__ cache_v, unsigned short* __restrict__ ctx) {
  __shared__ __align__(16) float Qt[32][130];
  __shared__ __align__(16) float Kt[32][130];
  __shared__ __align__(16) float Vt[32][132];
  __shared__ float wl[4][2][32];
  const int bx = blockIdx.x, h = blockIdx.y, b = blockIdx.z;
  const int tid = threadIdx.x, wave = tid >> 6, lane = tid & 63;
  const int half = lane >> 5, kl = lane & 31;
  const int q0 = bx * 32;
  const long slice = (long)(b * NH_ + h) * S_ * HD_;
  const float* Qg = q_rf + slice;
  const float* Kg = cache_k + slice;   // layer 0 (offset 0)
  const float* Vg = cache_v + slice;

  for (int idx = tid; idx < 32 * 128; idx += 256) {
    int r = idx >> 7, d = idx & 127;
    Qt[r][d] = Qg[(long)(q0 + r) * HD_ + d];
  }

  float out[4][4] = {};
  float m[4], l[4];
#pragma unroll
  for (int rp = 0; rp < 4; ++rp) { m[rp] = -1e30f; l[rp] = 0.0f; }
  const float scale = 0.088388347648318447f;  // 1/sqrt(128)

  const int nt = bx + 1;
  for (int t = 0; t < nt; ++t) {
    const int t0 = t * 32;
    __syncthreads();
    for (int idx = tid; idx < 32 * 128; idx += 256) {
      int r = idx >> 7, d = idx & 127;
      Kt[r][d] = Kg[(long)(t0 + r) * HD_ + d];
      Vt[r][d] = Vg[(long)(t0 + r) * HD_ + d];
    }
    __syncthreads();
#pragma unroll
    for (int rp = 0; rp < 4; ++rp) {
      const int lrow = wave * 8 + rp * 2 + half;
      const int srow = q0 + lrow;
      float a0 = 0.0f, a1 = 0.0f;
#pragma unroll
      for (int d = 0; d < 128; d += 4) {
        float2 q01 = *(const float2*)&Qt[lrow][d];
        float2 q23 = *(const float2*)&Qt[lrow][d + 2];
        float2 k01 = *(const float2*)&Kt[kl][d];
        float2 k23 = *(const float2*)&Kt[kl][d + 2];
        a0 = fmaf(q01.x, k01.x, a0); a0 = fmaf(q01.y, k01.y, a0);
        a1 = fmaf(q23.x, k23.x, a1); a1 = fmaf(q23.y, k23.y, a1);
      }
      float e = (t0 + kl <= srow) ? (a0 + a1) * scale : -1e30f;
      float mx = e;
      mx = fmaxf(mx, __shfl_xor(mx, 1));
      mx = fmaxf(mx, __shfl_xor(mx, 2));
      mx = fmaxf(mx, __shfl_xor(mx, 4));
      mx = fmaxf(mx, __shfl_xor(mx, 8));
      mx = fmaxf(mx, __shfl_xor(mx, 16));
      const float mnew = fmaxf(m[rp], mx);
      const float fac = __expf(m[rp] - mnew);
      const float w = __expf(e - mnew);
      m[rp] = mnew;
      float ws = w;
      ws += __shfl_xor(ws, 1); ws += __shfl_xor(ws, 2); ws += __shfl_xor(ws, 4);
      ws += __shfl_xor(ws, 8); ws += __shfl_xor(ws, 16);
      l[rp] = l[rp] * fac + ws;
      wl[wave][half][kl] = w;
      asm volatile("" ::: "memory");
#pragma unroll
      for (int j = 0; j < 4; ++j) out[rp][j] *= fac;
      for (int tt = 0; tt < 32; ++tt) {
        const float wv = wl[wave][half][tt];
        const float4 vv = *(const float4*)&Vt[tt][kl * 4];
        out[rp][0] = fmaf(wv, vv.x, out[rp][0]);
        out[rp][1] = fmaf(wv, vv.y, out[rp][1]);
        out[rp][2] = fmaf(wv, vv.z, out[rp][2]);
        out[rp][3] = fmaf(wv, vv.w, out[rp][3]);
      }
    }
  }

  // 3 diagonal entries (cache_k[1], cache_k[2], new k/v) + normalize + store
  const long layer = (long)B_ * NH_ * S_ * HD_;
#pragma unroll
  for (int rp = 0; rp < 4; ++rp) {
    const int lrow = wave * 8 + rp * 2 + half;
    const int srow = q0 + lrow;
    const long coff = slice + (long)srow * HD_;
    const float* k1 = cache_k + layer + coff;
    const float* k2 = cache_k + 2 * layer + coff;
    const long kvoff = ((long)(b * NKV_ + (h >> 1)) * S_ + srow) * HD_;
    const float* kn = k_rf + kvoff;
    float e1 = 0.0f, e2 = 0.0f, e3 = 0.0f;
#pragma unroll
    for (int j = 0; j < 4; ++j) {
      const float qd = Qt[lrow][kl * 4 + j];
      e1 = fmaf(qd, k1[kl * 4 + j], e1);
      e2 = fmaf(qd, k2[kl * 4 + j], e2);
      e3 = fmaf(qd, kn[kl * 4 + j], e3);
    }
#pragma unroll
    for (int off = 1; off < 32; off <<= 1) {
      e1 += __shfl_xor(e1, off);
      e2 += __shfl_xor(e2, off);
      e3 += __shfl_xor(e3, off);
    }
    e1 *= scale; e2 *= scale; e3 *= scale;
    const float M2 = fmaxf(fmaxf(e1, e2), fmaxf(e3, m[rp]));
    const float w1 = __expf(e1 - M2), w2 = __expf(e2 - M2), w3 = __expf(e3 - M2);
    const float wm = __expf(m[rp] - M2);
    const float Z = l[rp] * wm + w1 + w2 + w3;
    const float* v1 = cache_v + layer + coff;
    const float* v2 = cache_v + 2 * layer + coff;
    const float* vn = v_rf + kvoff;
    unsigned short* cp = ctx + ((long)b * S_ + srow) * (NH_ * HD_) + h * HD_ + kl * 4;
#pragma unroll
    for (int j = 0; j < 4; ++j) {
      const float o = (out[rp][j] * wm + w1 * v1[kl * 4 + j] + w2 * v2[kl * 4 + j]
                       + w3 * vn[kl * 4 + j]) / Z;
      cp[j] = f2bf(o);
    }
  }
}

// ------------- hidden = hs + attn_out ; hn = rms(hidden)*post_w (bf16) -------------
__global__ __launch_bounds__(256)
void add_rms(const float* __restrict__ hs, const float* __restrict__ ao,
             const float* __restrict__ post_w, float* __restrict__ hidden,
             unsigned short* __restrict__ hn) {
  __shared__ float red[4];
  const int row = blockIdx.x, tid = threadIdx.x;
  const float* p = hs + (long)row * H_;
  const float* q = ao + (long)row * H_;
  f4 a = ((const f4*)p)[tid] + ((const f4*)q)[tid];
  f4 b = ((const f4*)p)[tid + 256] + ((const f4*)q)[tid + 256];
  f4* ho = (f4*)(hidden + (long)row * H_);
  ho[tid] = a;
  ho[tid + 256] = b;
  float ss = a.x*a.x + a.y*a.y + a.z*a.z + a.w*a.w + b.x*b.x + b.y*b.y + b.z*b.z + b.w*b.w;
  float sc = rsqrtf(block_reduce_sum(ss, red) * (1.0f / H_) + 1e-6f);
  unsigned short* o = hn + (long)row * H_;
#pragma unroll
  for (int j = 0; j < 4; ++j) {
    o[tid * 4 + j]        = f2bf(a[j] * sc * post_w[tid * 4 + j]);
    o[1024 + tid * 4 + j] = f2bf(b[j] * sc * post_w[1024 + tid * 4 + j]);
  }
}

// ------------- act = silu(g)*u (bf16), in-place over g is safe (same index) -------------
__global__ __launch_bounds__(256)
void silu_mul(const unsigned short* __restrict__ g, const unsigned short* __restrict__ u,
              unsigned short* __restrict__ act) {
  const long i = ((long)blockIdx.x * 256 + threadIdx.x) * 8;
  bf16x8 gv = *(const bf16x8*)(g + i);
  bf16x8 uv = *(const bf16x8*)(u + i);
  bf16x8 r;
#pragma unroll
  for (int j = 0; j < 8; ++j) {
    float gf = bf2f((unsigned short)gv[j]);
    float uf = bf2f((unsigned short)uv[j]);
    float sl = gf / (1.0f + __expf(-gf));
    r[j] = (short)f2bf(sl * uf);
  }
  *(bf16x8*)(act + i) = r;
}

// ------------- out = hidden + mlp -------------
__global__ __launch_bounds__(256)
void final_add(const float* __restrict__ hidden, const float* __restrict__ mlp,
               float* __restrict__ out) {
  const long i = ((long)blockIdx.x * 256 + threadIdx.x) * 4;
  *(f4*)(out + i) = *(const f4*)(hidden + i) + *(const f4*)(mlp + i);
}

extern "C" void kernel_launch(void* const* d_in, const int* in_sizes, int n_in,
                              void* d_out, int out_size, void* d_ws, size_t ws_size,
                              hipStream_t stream) {
  const float* input_emb     = (const float*)d_in[0];
  const float* hidden_states = (const float*)d_in[1];
  const float* cache_k       = (const float*)d_in[2];
  const float* cache_v       = (const float*)d_in[3];
  const float* Wq            = (const float*)d_in[4];
  const float* Wk            = (const float*)d_in[5];
  const float* Wv            = (const float*)d_in[6];
  const float* Wo            = (const float*)d_in[7];
  const float* Wg            = (const float*)d_in[8];
  const float* Wu            = (const float*)d_in[9];
  const float* Wd            = (const float*)d_in[10];
  const float* hn_w          = (const float*)d_in[11];
  const float* in_w          = (const float*)d_in[12];
  const float* post_w        = (const float*)d_in[13];
  // d_in[14] = attention_mask (pure causal; re-derived in-kernel)
  const float* cosb          = (const float*)d_in[15];
  const float* sinb          = (const float*)d_in[16];
  float* out = (float*)d_out;

  char* wp = (char*)d_ws;
  auto alloc = [&](size_t nbytes) {
    char* p = wp;
    wp += (nbytes + 255) & ~(size_t)255;
    return p;
  };
  unsigned short* x   = (unsigned short*)alloc((size_t)M_ * 2 * H_ * 2);  // 32MB
  unsigned short* WqT = (unsigned short*)alloc((size_t)2048 * 4096 * 2);  // 16MB
  unsigned short* WkT = (unsigned short*)alloc((size_t)1024 * 4096 * 2);  // 8MB
  unsigned short* WvT = (unsigned short*)alloc((size_t)1024 * 4096 * 2);  // 8MB
  unsigned short* WoT = (unsigned short*)alloc((size_t)2048 * 2048 * 2);
  unsigned short* WgT = (unsigned short*)alloc((size_t)6144 * 2048 * 2);
  unsigned short* WuT = (unsigned short*)alloc((size_t)6144 * 2048 * 2);
  unsigned short* WdT = (unsigned short*)alloc((size_t)2048 * 6144 * 2);
  float* qf   = (float*)alloc((size_t)M_ * 2048 * 4);
  float* kf   = (float*)alloc((size_t)M_ * 1024 * 4);
  float* vf   = (float*)alloc((size_t)M_ * 1024 * 4);
  float* k_rf = (float*)alloc((size_t)B_ * NKV_ * S_ * HD_ * 4);
  float* v_rf = (float*)alloc((size_t)B_ * NKV_ * S_ * HD_ * 4);
  float* hidden       = (float*)alloc((size_t)M_ * H_ * 4);
  unsigned short* g   = (unsigned short*)alloc((size_t)M_ * I_ * 2);
  unsigned short* u   = (unsigned short*)alloc((size_t)M_ * I_ * 2);
  // Reused regions (dead buffers):
  float* q_rf = (float*)WqT;                  // 32MB: WqT+WkT+WvT dead after QKV GEMMs
  unsigned short* ctx = x;                    // x dead after QKV GEMMs (16MB)
  unsigned short* hn  = x + (size_t)M_ * H_;  // second half of x (16MB)
  unsigned short* act = g;                    // in-place silu (same-index)
  float* attn_out = qf;                       // qf dead after rope_qkv
  float* mlp = kf;                            // kf+vf contiguous 32MB, dead after rope_qkv

  // 1) weight transpose-converts (Bt layout, bf16)
  transpose_cvt_z<<<dim3(2048 / 32, 4096 / 32, 1), 256, 0, stream>>>(Wq, WqT, 4096, 2048);
  transpose_cvt_z<<<dim3(1024 / 32, 4096 / 32, 1), 256, 0, stream>>>(Wk, WkT, 4096, 1024);
  transpose_cvt_z<<<dim3(1024 / 32, 4096 / 32, 1), 256, 0, stream>>>(Wv, WvT, 4096, 1024);
  transpose_cvt_z<<<dim3(2048 / 32, 2048 / 32, 1), 256, 0, stream>>>(Wo, WoT, 2048, 2048);
  transpose_cvt_z<<<dim3(6144 / 32, 2048 / 32, 1), 256, 0, stream>>>(Wg, WgT, 2048, 6144);
  transpose_cvt_z<<<dim3(6144 / 32, 2048 / 32, 1), 256, 0, stream>>>(Wu, WuT, 2048, 6144);
  transpose_cvt_z<<<dim3(2048 / 32, 6144 / 32, 1), 256, 0, stream>>>(Wd, WdT, 6144, 2048);
  // 2) fused RMS norms -> x
  rms_concat<<<M_, 256, 0, stream>>>(input_emb, hidden_states, in_w, hn_w, x);
  // 3) QKV projections
  gemm_bt<0><<<dim3(2048 / 128, M_ / 128), 256, 0, stream>>>(x, WqT, qf, M_, 2048, 4096);
  gemm_bt<0><<<dim3(1024 / 128, M_ / 128), 256, 0, stream>>>(x, WkT, kf, M_, 1024, 4096);
  gemm_bt<0><<<dim3(1024 / 128, M_ / 128), 256, 0, stream>>>(x, WvT, vf, M_, 1024, 4096);
  // 4) RoPE + layout (fp32 outputs; q_rf overlays dead WqT/WkT/WvT)
  rope_qkv<<<M_, 256, 0, stream>>>(qf, kf, vf, cosb, sinb, q_rf, k_rf, v_rf);
  // 5) simple fp32 attention (flash-style online softmax + 3 diag entries) -> ctx
  attn_simple<<<dim3(S_ / 32, NH_, B_), 256, 0, stream>>>(q_rf, k_rf, v_rf, cache_k, cache_v, ctx);
  // 6) output projection
  gemm_bt<0><<<dim3(2048 / 128, M_ / 128), 256, 0, stream>>>(ctx, WoT, attn_out, M_, 2048, 2048);
  // 7) residual add + post-rms
  add_rms<<<M_, 256, 0, stream>>>(hidden_states, attn_out, post_w, hidden, hn);
  // 8) MLP
  gemm_bt<1><<<dim3(6144 / 128, M_ / 128), 256, 0, stream>>>(hn, WgT, g, M_, 6144, 2048);
  gemm_bt<1><<<dim3(6144 / 128, M_ / 128), 256, 0, stream>>>(hn, WuT, u, M_, 6144, 2048);
  silu_mul<<<(M_ * I_) / (8 * 256), 256, 0, stream>>>(g, u, act);
  gemm_bt<0><<<dim3(2048 / 128, M_ / 128), 256, 0, stream>>>(act, WdT, mlp, M_, 2048, 6144);
  final_add<<<(M_ * H_) / (4 * 256), 256, 0, stream>>>(hidden, mlp, out);
}